// Round 9
// baseline (2164.130 us; speedup 1.0000x reference)
//
#include <hip/hip_runtime.h>
#include <hip/hip_bf16.h>

// 2-layer LSTM (T=1024, B=512, IN=20, H1=128, H2=64) + head OUT=3.
// Only batch row 511 feeds the output => single-sequence scan.
//
// Pipeline:
//   A : xp1 = x[:,511,:] @ W_ih0^T + b0            (parallel)
//   B1: layer-1 scan                                (serial, 1 CU)
//   C1: xp2 = h1seq @ W_ih1^T + b1                 (parallel GEMM)
//   B2: layer-2 scan                                (serial, 1 CU)
//   D : head                                        (parallel)
//
// Round-9 (= R8 with the macro compile error fixed): pin weights into the
// ACC half of the unified register file explicitly (v_accvgpr_write at init,
// v_accvgpr_read at use — 1-cyc VALU, no memory). The allocator repeatedly
// granted only the arch half (64/128) and streamed weights through L2
// (~256KB/step = 1us/step floor). Pointwise phase replicated across waves.

#define T_STEPS 1024
#define BATCH   512
#define IN_F    20
#define H1_     128
#define H2_     64
#define OUT_F   3
#define G1_     (4*H1_)   // 512
#define G2_     (4*H2_)   // 256

typedef float f4 __attribute__((ext_vector_type(4)));

__device__ __forceinline__ float sigmoidf_(float x) {
    return 1.0f / (1.0f + __expf(-x));
}
__device__ __forceinline__ float tanhf_(float x) {
    return 1.0f - 2.0f / (__expf(2.0f * x) + 1.0f);
}

#define REP8(M)  M(0) M(1) M(2) M(3) M(4) M(5) M(6) M(7)
#define REP16(M) REP8(M) M(8) M(9) M(10) M(11) M(12) M(13) M(14) M(15)

// Declare 4 AGPR-resident floats for quad q
#define ADECL(q) float ag##q##_0, ag##q##_1, ag##q##_2, ag##q##_3;
// Load quad q from PTR and pin into AGPRs
#define APIN(q, PTR) { const f4 wq_ = (PTR)[q];                               \
    asm volatile("v_accvgpr_write_b32 %0, %1" : "=a"(ag##q##_0) : "v"(wq_.x));\
    asm volatile("v_accvgpr_write_b32 %0, %1" : "=a"(ag##q##_1) : "v"(wq_.y));\
    asm volatile("v_accvgpr_write_b32 %0, %1" : "=a"(ag##q##_2) : "v"(wq_.z));\
    asm volatile("v_accvgpr_write_b32 %0, %1" : "=a"(ag##q##_3) : "v"(wq_.w));}
// Read quad q back and accumulate against LDS h-quad
#define AFMA(q, HB)                                                           \
    { const f4 h4_ = (HB)[q]; float wx_, wy_, wz_, ww_;                       \
      asm volatile("v_accvgpr_read_b32 %0, %1" : "=v"(wx_) : "a"(ag##q##_0)); \
      asm volatile("v_accvgpr_read_b32 %0, %1" : "=v"(wy_) : "a"(ag##q##_1)); \
      asm volatile("v_accvgpr_read_b32 %0, %1" : "=v"(wz_) : "a"(ag##q##_2)); \
      asm volatile("v_accvgpr_read_b32 %0, %1" : "=v"(ww_) : "a"(ag##q##_3)); \
      ax = fmaf(wx_, h4_.x, ax); ay = fmaf(wy_, h4_.y, ay);                   \
      az = fmaf(wz_, h4_.z, az); aw = fmaf(ww_, h4_.w, aw); }

// ---------------- A: x-projection for batch row 511 --------------------------
__global__ void xproj_kernel(const float* __restrict__ x,
                             const float* __restrict__ W_ih0,
                             const float* __restrict__ b_ih0,
                             const float* __restrict__ b_hh0,
                             float* __restrict__ xp1)
{
    const int t = blockIdx.x;
    const int g = threadIdx.x;
    const float* xr = x + ((size_t)t * BATCH + (BATCH - 1)) * IN_F;
    const float* w  = W_ih0 + g * IN_F;
    float acc = b_ih0[g] + b_hh0[g];
#pragma unroll
    for (int i = 0; i < IN_F; ++i) acc = fmaf(xr[i], w[i], acc);
    xp1[t * G1_ + g] = acc;
}

// ---------------- B1: layer-1 scan (serial, one block) -----------------------
// 1024 threads. g = tid&511 (gate), hf = tid>>9 (column half, wave-uniform).
// Weights: W_hh0[g][hf*64 .. hf*64+64) = 16 quads pinned in AGPRs.
// Partials: sp1[g*3+hf] (stride 3, conflict-free). Pointwise replicated 8x.
__global__ __attribute__((amdgpu_flat_work_group_size(1024, 1024),
                          amdgpu_waves_per_eu(4, 4)))
void lstm1_kernel(const float* __restrict__ xp1,
                  const float* __restrict__ W_hh0,
                  float* __restrict__ h1seq)
{
    const int tid = threadIdx.x;
    const int g   = tid & 511;
    const int hf  = tid >> 9;          // wave-uniform
    const int hi  = tid & 127;         // replicated h index

    __shared__ f4    sh1[H1_ / 4];     // h1 state (128 f32)
    __shared__ float sp1[G1_ * 3];     // partials, stride 3 (6 KB)

    const f4* pw = (const f4*)(W_hh0 + (size_t)g * H1_ + hf * 64);
    REP16(ADECL)
#define APIN1(q) APIN(q, pw)
    REP16(APIN1)
#undef APIN1

    if (tid < H1_ / 4) sh1[tid] = f4{0.f, 0.f, 0.f, 0.f};
    float c1 = 0.0f;                   // replicated per h-index
    __syncthreads();

    const f4* hb = sh1 + hf * 16;
    float xp_cur = (hf == 0) ? xp1[g] : 0.0f;

    for (int t = 0; t < T_STEPS; ++t) {
        float xp_next = 0.0f;
        {
            const int tn = (t + 1 < T_STEPS) ? (t + 1) : (T_STEPS - 1);
            if (hf == 0) xp_next = xp1[(size_t)tn * G1_ + g];
        }

        float ax = 0.f, ay = 0.f, az = 0.f, aw = 0.f;
#define P1S(k) AFMA(k, hb)
        REP16(P1S)
#undef P1S
        sp1[g * 3 + hf] = ((ax + ay) + (az + aw)) + xp_cur;
        __syncthreads();   // sp1 ready (also orders prev h1 writes)

        // ---- pointwise, replicated across all waves (private c1 copies) ----
        {
            const float vi = sp1[hi * 3]            + sp1[hi * 3 + 1];
            const float vf = sp1[(H1_   + hi) * 3]  + sp1[(H1_   + hi) * 3 + 1];
            const float vg = sp1[(2*H1_ + hi) * 3]  + sp1[(2*H1_ + hi) * 3 + 1];
            const float vo = sp1[(3*H1_ + hi) * 3]  + sp1[(3*H1_ + hi) * 3 + 1];
            c1 = fmaf(sigmoidf_(vf), c1, sigmoidf_(vi) * tanhf_(vg));
            const float h = sigmoidf_(vo) * tanhf_(c1);
            if (tid < H1_) {
                ((float*)sh1)[tid] = h;
                h1seq[(size_t)t * H1_ + tid] = h;   // fire-and-forget
            }
        }
        __syncthreads();   // h1_new ready
        xp_cur = xp_next;
    }
}

// ---------------- C1: xp2 = h1seq @ W_ih1^T + (b_ih1 + b_hh1) ---------------
__global__ void xproj2_kernel(const float* __restrict__ h1seq,
                              const float* __restrict__ W_ih1,
                              const float* __restrict__ b_ih1,
                              const float* __restrict__ b_hh1,
                              float* __restrict__ xp2)
{
    const int t = blockIdx.x;
    const int g = threadIdx.x;
    __shared__ f4 sh[H1_ / 4];
    if (g < H1_ / 4) sh[g] = ((const f4*)(h1seq + (size_t)t * H1_))[g];
    __syncthreads();
    const f4* w = (const f4*)(W_ih1 + (size_t)g * H1_);
    float ax = 0.f, ay = 0.f, az = 0.f, aw = 0.f;
#pragma unroll
    for (int k = 0; k < H1_ / 4; ++k) {
        const f4 h4 = sh[k]; const f4 w4 = w[k];
        ax = fmaf(w4.x, h4.x, ax); ay = fmaf(w4.y, h4.y, ay);
        az = fmaf(w4.z, h4.z, az); aw = fmaf(w4.w, h4.w, aw);
    }
    xp2[(size_t)t * G2_ + g] = ((ax + ay) + (az + aw)) + b_ih1[g] + b_hh1[g];
}

// ---------------- B2: layer-2 scan (serial, one block) -----------------------
// 512 threads. g2 = tid&255 (gate), hf = tid>>8. 8 quads pinned in AGPRs.
// Partials sp2[g2*3+hf]. Pointwise replicated (hi = tid&63).
__global__ __attribute__((amdgpu_flat_work_group_size(512, 512),
                          amdgpu_waves_per_eu(2, 2)))
void lstm2_kernel(const float* __restrict__ xp2,
                  const float* __restrict__ W_hh1,
                  float* __restrict__ h2seq)
{
    const int tid = threadIdx.x;
    const int g2  = tid & 255;
    const int hf  = tid >> 8;          // wave-uniform
    const int hi  = tid & 63;

    __shared__ f4    sh2[H2_ / 4];     // h2 state (64 f32)
    __shared__ float sp2[G2_ * 3];     // partials, stride 3 (3 KB)

    const f4* pw = (const f4*)(W_hh1 + (size_t)g2 * H2_ + hf * 32);
    REP8(ADECL)
#define APIN2(q) APIN(q, pw)
    REP8(APIN2)
#undef APIN2

    if (tid < H2_ / 4) sh2[tid] = f4{0.f, 0.f, 0.f, 0.f};
    float c2 = 0.0f;                   // replicated per h-index
    __syncthreads();

    const f4* hb = sh2 + hf * 8;
    float xp_cur = (hf == 0) ? xp2[g2] : 0.0f;

    for (int t = 0; t < T_STEPS; ++t) {
        float xp_next = 0.0f;
        {
            const int tn = (t + 1 < T_STEPS) ? (t + 1) : (T_STEPS - 1);
            if (hf == 0) xp_next = xp2[(size_t)tn * G2_ + g2];
        }

        float ax = 0.f, ay = 0.f, az = 0.f, aw = 0.f;
#define P2S(k) AFMA(k, hb)
        REP8(P2S)
#undef P2S
        sp2[g2 * 3 + hf] = ((ax + ay) + (az + aw)) + xp_cur;
        __syncthreads();   // sp2 ready (also orders prev h2 writes)

        {
            const float vi = sp2[hi * 3]           + sp2[hi * 3 + 1];
            const float vf = sp2[(H2_   + hi) * 3] + sp2[(H2_   + hi) * 3 + 1];
            const float vg = sp2[(2*H2_ + hi) * 3] + sp2[(2*H2_ + hi) * 3 + 1];
            const float vo = sp2[(3*H2_ + hi) * 3] + sp2[(3*H2_ + hi) * 3 + 1];
            c2 = fmaf(sigmoidf_(vf), c2, sigmoidf_(vi) * tanhf_(vg));
            const float h = sigmoidf_(vo) * tanhf_(c2);
            if (tid < H2_) {
                ((float*)sh2)[tid] = h;
                h2seq[(size_t)t * H2_ + tid] = h;
            }
        }
        __syncthreads();   // h2_new ready
        xp_cur = xp_next;
    }
}

// ---------------- D: head out[t,o] = relu(h2[t]) . W_d[o] + b_d --------------
__global__ void head_kernel(const float* __restrict__ h2seq,
                            const float* __restrict__ W_d,
                            const float* __restrict__ b_d,
                            float* __restrict__ out)
{
    const int idx = blockIdx.x * blockDim.x + threadIdx.x;
    if (idx >= T_STEPS * OUT_F) return;
    const int t = idx / OUT_F;
    const int o = idx - t * OUT_F;
    const float* hr = h2seq + (size_t)t * H2_;
    const float* w  = W_d + o * H2_;
    float acc = b_d[o];
#pragma unroll
    for (int j = 0; j < H2_; ++j) acc = fmaf(fmaxf(hr[j], 0.0f), w[j], acc);
    out[idx] = acc;
}

extern "C" void kernel_launch(void* const* d_in, const int* in_sizes, int n_in,
                              void* d_out, int out_size, void* d_ws, size_t ws_size,
                              hipStream_t stream) {
    const float* x     = (const float*)d_in[0];
    const float* W_ih0 = (const float*)d_in[1];
    const float* W_hh0 = (const float*)d_in[2];
    const float* b_ih0 = (const float*)d_in[3];
    const float* b_hh0 = (const float*)d_in[4];
    const float* W_ih1 = (const float*)d_in[5];
    const float* W_hh1 = (const float*)d_in[6];
    const float* b_ih1 = (const float*)d_in[7];
    const float* b_hh1 = (const float*)d_in[8];
    const float* W_d   = (const float*)d_in[9];
    const float* b_d   = (const float*)d_in[10];

    float* out   = (float*)d_out;
    float* xp1   = (float*)d_ws;                       // [1024][512] = 2 MB
    float* h1seq = xp1 + (size_t)T_STEPS * G1_;        // [1024][128] = 512 KB
    float* h2seq = h1seq + (size_t)T_STEPS * H1_;      // [1024][64]  = 256 KB
    float* xp2   = xp1;                                // overlay (xp1 dead after B1)

    hipLaunchKernelGGL(xproj_kernel, dim3(T_STEPS), dim3(G1_), 0, stream,
                       x, W_ih0, b_ih0, b_hh0, xp1);
    hipLaunchKernelGGL(lstm1_kernel, dim3(1), dim3(1024), 0, stream,
                       xp1, W_hh0, h1seq);
    hipLaunchKernelGGL(xproj2_kernel, dim3(T_STEPS), dim3(G2_), 0, stream,
                       h1seq, W_ih1, b_ih1, b_hh1, xp2);
    hipLaunchKernelGGL(lstm2_kernel, dim3(1), dim3(512), 0, stream,
                       xp2, W_hh1, h2seq);
    hipLaunchKernelGGL(head_kernel, dim3((T_STEPS * OUT_F + 255) / 256), dim3(256),
                       0, stream, h2seq, W_d, b_d, out);
}

// Round 10
// 1864.350 us; speedup vs baseline: 1.1608x; 1.1608x over previous
//
#include <hip/hip_runtime.h>
#include <hip/hip_bf16.h>

// 2-layer LSTM (T=1024, B=512, IN=20, H1=128, H2=64) + head OUT=3.
// Only batch row 511 feeds the output => single-sequence scan.
//
// Pipeline:
//   A : xp1 = x[:,511,:] @ W_ih0^T + b0            (parallel)
//   B1: layer-1 scan — MFMA, weights in hard AGPRs (serial, 1 CU)
//   C1: xp2 = h1seq @ W_ih1^T + b1                 (parallel GEMM)
//   B2: layer-2 scan                                (serial, 1 CU)
//   D : head                                        (parallel)
//
// Round-10: R2-R9 proved any scheme where weights transit memory or VALU per
// use floors at ~1us/step (stream) or worse (accvgpr_read: R9). MFMA is the
// only op that reads AGPRs directly as math operands. lstm1 = f16 hi/lo
// 3-term MFMA matvec (error ~2^-22), weights pinned ONCE into physical
// a0..a127 via v_accvgpr_write asm. B operand = h broadcast to all 16 cols
// (built from LDS f16 arrays each step); col-0 lanes extract gates.

#define T_STEPS 1024
#define BATCH   512
#define IN_F    20
#define H1_     128
#define H2_     64
#define OUT_F   3
#define G1_     (4*H1_)   // 512
#define G2_     (4*H2_)   // 256

typedef float f4 __attribute__((ext_vector_type(4)));
typedef _Float16 h8 __attribute__((ext_vector_type(8)));
typedef unsigned int u32;

__device__ __forceinline__ float sigmoidf_(float x) {
    return 1.0f / (1.0f + __expf(-x));
}
__device__ __forceinline__ float tanhf_(float x) {
    return 1.0f - 2.0f / (__expf(2.0f * x) + 1.0f);
}
__device__ __forceinline__ u32 pkh(_Float16 a, _Float16 b) {
    union { _Float16 h[2]; u32 u; } cv; cv.h[0] = a; cv.h[1] = b; return cv.u;
}

#define REP16(M) M(0) M(1) M(2) M(3) M(4) M(5) M(6) M(7) \
                 M(8) M(9) M(10) M(11) M(12) M(13) M(14) M(15)

// R7 weight loader for lstm2 (asm loads; known-good)
#define ASM_LOAD_16Q(PTR)                                                     \
    asm volatile(                                                             \
        "global_load_dwordx4 %0,  %16, off\n\t"                              \
        "global_load_dwordx4 %1,  %16, off offset:16\n\t"                    \
        "global_load_dwordx4 %2,  %16, off offset:32\n\t"                    \
        "global_load_dwordx4 %3,  %16, off offset:48\n\t"                    \
        "global_load_dwordx4 %4,  %16, off offset:64\n\t"                    \
        "global_load_dwordx4 %5,  %16, off offset:80\n\t"                    \
        "global_load_dwordx4 %6,  %16, off offset:96\n\t"                    \
        "global_load_dwordx4 %7,  %16, off offset:112\n\t"                   \
        "global_load_dwordx4 %8,  %16, off offset:128\n\t"                   \
        "global_load_dwordx4 %9,  %16, off offset:144\n\t"                   \
        "global_load_dwordx4 %10, %16, off offset:160\n\t"                   \
        "global_load_dwordx4 %11, %16, off offset:176\n\t"                   \
        "global_load_dwordx4 %12, %16, off offset:192\n\t"                   \
        "global_load_dwordx4 %13, %16, off offset:208\n\t"                   \
        "global_load_dwordx4 %14, %16, off offset:224\n\t"                   \
        "global_load_dwordx4 %15, %16, off offset:240\n\t"                   \
        "s_waitcnt vmcnt(0)"                                                  \
        : "=&v"(w_0), "=&v"(w_1), "=&v"(w_2), "=&v"(w_3),                    \
          "=&v"(w_4), "=&v"(w_5), "=&v"(w_6), "=&v"(w_7),                    \
          "=&v"(w_8), "=&v"(w_9), "=&v"(w_10), "=&v"(w_11),                  \
          "=&v"(w_12), "=&v"(w_13), "=&v"(w_14), "=&v"(w_15)                 \
        : "v"(PTR))

// Pin one dword into a named physical AGPR
#define PIN1(R, V) asm volatile("v_accvgpr_write_b32 " R ", %0" :: "v"((u32)(V)) : R)

// One MFMA: ACC += A(agpr range) x B(vgpr quad)
#define MF(ACC, AR, B) \
    asm volatile("v_mfma_f32_16x16x32_f16 %0, " AR ", %1, %0" : "+v"(ACC) : "v"(B))

// Load W rows for (M,KT), split f16 hi/lo, pin 8 dwords into AGPRs.
#define FRAG(M, KT, R0,R1,R2,R3,R4,R5,R6,R7) do {                             \
    const float* wp_ = W_hh0 + (size_t)(64*w + 16*(M) + lr) * H1_             \
                       + (KT)*32 + kq*8;                                      \
    f4 xa_ = *(const f4*)wp_; f4 xb_ = *(const f4*)(wp_ + 4);                 \
    _Float16 h0_=(_Float16)xa_.x, h1_=(_Float16)xa_.y,                        \
             h2_=(_Float16)xa_.z, h3_=(_Float16)xa_.w,                        \
             h4_=(_Float16)xb_.x, h5_=(_Float16)xb_.y,                        \
             h6_=(_Float16)xb_.z, h7_=(_Float16)xb_.w;                        \
    _Float16 l0_=(_Float16)(xa_.x-(float)h0_), l1_=(_Float16)(xa_.y-(float)h1_),\
             l2_=(_Float16)(xa_.z-(float)h2_), l3_=(_Float16)(xa_.w-(float)h3_),\
             l4_=(_Float16)(xb_.x-(float)h4_), l5_=(_Float16)(xb_.y-(float)h5_),\
             l6_=(_Float16)(xb_.z-(float)h6_), l7_=(_Float16)(xb_.w-(float)h7_);\
    PIN1(R0, pkh(h0_,h1_)); PIN1(R1, pkh(h2_,h3_));                           \
    PIN1(R2, pkh(h4_,h5_)); PIN1(R3, pkh(h6_,h7_));                           \
    PIN1(R4, pkh(l0_,l1_)); PIN1(R5, pkh(l2_,l3_));                           \
    PIN1(R6, pkh(l4_,l5_)); PIN1(R7, pkh(l6_,l7_));                           \
} while (0)

// ---------------- A: x-projection for batch row 511 --------------------------
__global__ void xproj_kernel(const float* __restrict__ x,
                             const float* __restrict__ W_ih0,
                             const float* __restrict__ b_ih0,
                             const float* __restrict__ b_hh0,
                             float* __restrict__ xp1)
{
    const int t = blockIdx.x;
    const int g = threadIdx.x;
    const float* xr = x + ((size_t)t * BATCH + (BATCH - 1)) * IN_F;
    const float* w  = W_ih0 + g * IN_F;
    float acc = b_ih0[g] + b_hh0[g];
#pragma unroll
    for (int i = 0; i < IN_F; ++i) acc = fmaf(xr[i], w[i], acc);
    xp1[t * G1_ + g] = acc;
}

// ---------------- B1: layer-1 scan — MFMA version ----------------------------
// 512 thr = 8 waves (2/SIMD, 256-reg unified budget: 128 AGPR wt + ~100 arch).
// Wave w owns rows [64w,64w+64): 4 M-tiles x 4 K-tiles, hi/lo f16 frags in
// a0..a127. Per step: B = h bcast (LDS f16), 48 MFMAs, col0 lanes write gates.
__global__ __attribute__((amdgpu_flat_work_group_size(512, 512),
                          amdgpu_waves_per_eu(2, 2)))
void lstm1_kernel(const float* __restrict__ xp1,
                  const float* __restrict__ W_hh0,
                  float* __restrict__ h1seq)
{
    const int tid = threadIdx.x;
    const int w   = tid >> 6;          // wave 0..7
    const int l   = tid & 63;          // lane
    const int lr  = l & 15;            // A row-in-tile
    const int kq  = l >> 4;            // k-chunk 0..3 (8 f16 each)

    __shared__ float sg[G1_];          // gate pre-activations (2 KB)
    __shared__ h8    sh_hi8[16];       // h_hi  f16[128]
    __shared__ h8    sh_lo8[16];       // h_lo  f16[128]

    // ---- pin W_hh0 fragments into physical AGPRs a0..a127 (once) -----------
    FRAG(0,0,"a0","a1","a2","a3","a4","a5","a6","a7");
    FRAG(0,1,"a8","a9","a10","a11","a12","a13","a14","a15");
    FRAG(0,2,"a16","a17","a18","a19","a20","a21","a22","a23");
    FRAG(0,3,"a24","a25","a26","a27","a28","a29","a30","a31");
    FRAG(1,0,"a32","a33","a34","a35","a36","a37","a38","a39");
    FRAG(1,1,"a40","a41","a42","a43","a44","a45","a46","a47");
    FRAG(1,2,"a48","a49","a50","a51","a52","a53","a54","a55");
    FRAG(1,3,"a56","a57","a58","a59","a60","a61","a62","a63");
    FRAG(2,0,"a64","a65","a66","a67","a68","a69","a70","a71");
    FRAG(2,1,"a72","a73","a74","a75","a76","a77","a78","a79");
    FRAG(2,2,"a80","a81","a82","a83","a84","a85","a86","a87");
    FRAG(2,3,"a88","a89","a90","a91","a92","a93","a94","a95");
    FRAG(3,0,"a96","a97","a98","a99","a100","a101","a102","a103");
    FRAG(3,1,"a104","a105","a106","a107","a108","a109","a110","a111");
    FRAG(3,2,"a112","a113","a114","a115","a116","a117","a118","a119");
    FRAG(3,3,"a120","a121","a122","a123","a124","a125","a126","a127");

    if (tid < 16) { sh_hi8[tid] = (h8)0; sh_lo8[tid] = (h8)0; }
    float c1 = 0.0f;                   // owned by tid < 128
    __syncthreads();

    // xp prefetch base: rows 64w+16m+kq*4 .. +4
    const float* xb = xp1 + 64 * w + kq * 4;
    f4 xq0 = *(const f4*)(xb);
    f4 xq1 = *(const f4*)(xb + 16);
    f4 xq2 = *(const f4*)(xb + 32);
    f4 xq3 = *(const f4*)(xb + 48);

    for (int t = 0; t < T_STEPS; ++t) {
        // ---- B fragments from LDS (16-lane broadcast reads) ----------------
        const h8 bh0 = sh_hi8[kq],      bl0 = sh_lo8[kq];
        const h8 bh1 = sh_hi8[4 + kq],  bl1 = sh_lo8[4 + kq];
        const h8 bh2 = sh_hi8[8 + kq],  bl2 = sh_lo8[8 + kq];
        const h8 bh3 = sh_hi8[12 + kq], bl3 = sh_lo8[12 + kq];

        // ---- acc init = xp (biases folded); then prefetch next t -----------
        f4 ac0 = xq0, ac1 = xq1, ac2 = xq2, ac3 = xq3;
        {
            const int tn = (t + 1 < T_STEPS) ? (t + 1) : (T_STEPS - 1);
            const float* xn = xb + (size_t)tn * G1_;
            xq0 = *(const f4*)(xn);
            xq1 = *(const f4*)(xn + 16);
            xq2 = *(const f4*)(xn + 32);
            xq3 = *(const f4*)(xn + 48);
        }
        // hazard guard: VALU writes of acc/B before MFMA reads
        asm volatile("s_nop 3" : "+v"(ac0), "+v"(ac1), "+v"(ac2), "+v"(ac3));

        // ---- 48 MFMAs: terms (hi,Bhi),(hi,Blo),(lo,Bhi) per K-tile ---------
        MF(ac0,"a[0:3]",bh0);   MF(ac1,"a[32:35]",bh0);  MF(ac2,"a[64:67]",bh0);  MF(ac3,"a[96:99]",bh0);
        MF(ac0,"a[0:3]",bl0);   MF(ac1,"a[32:35]",bl0);  MF(ac2,"a[64:67]",bl0);  MF(ac3,"a[96:99]",bl0);
        MF(ac0,"a[4:7]",bh0);   MF(ac1,"a[36:39]",bh0);  MF(ac2,"a[68:71]",bh0);  MF(ac3,"a[100:103]",bh0);

        MF(ac0,"a[8:11]",bh1);  MF(ac1,"a[40:43]",bh1);  MF(ac2,"a[72:75]",bh1);  MF(ac3,"a[104:107]",bh1);
        MF(ac0,"a[8:11]",bl1);  MF(ac1,"a[40:43]",bl1);  MF(ac2,"a[72:75]",bl1);  MF(ac3,"a[104:107]",bl1);
        MF(ac0,"a[12:15]",bh1); MF(ac1,"a[44:47]",bh1);  MF(ac2,"a[76:79]",bh1);  MF(ac3,"a[108:111]",bh1);

        MF(ac0,"a[16:19]",bh2); MF(ac1,"a[48:51]",bh2);  MF(ac2,"a[80:83]",bh2);  MF(ac3,"a[112:115]",bh2);
        MF(ac0,"a[16:19]",bl2); MF(ac1,"a[48:51]",bl2);  MF(ac2,"a[80:83]",bl2);  MF(ac3,"a[112:115]",bl2);
        MF(ac0,"a[20:23]",bh2); MF(ac1,"a[52:55]",bh2);  MF(ac2,"a[84:87]",bh2);  MF(ac3,"a[116:119]",bh2);

        MF(ac0,"a[24:27]",bh3); MF(ac1,"a[56:59]",bh3);  MF(ac2,"a[88:91]",bh3);  MF(ac3,"a[120:123]",bh3);
        MF(ac0,"a[24:27]",bl3); MF(ac1,"a[56:59]",bl3);  MF(ac2,"a[88:91]",bl3);  MF(ac3,"a[120:123]",bl3);
        MF(ac0,"a[28:31]",bh3); MF(ac1,"a[60:63]",bh3);  MF(ac2,"a[92:95]",bh3);  MF(ac3,"a[124:127]",bh3);

        // hazard guard: MFMA writes -> LDS reads of acc regs
        asm volatile("s_nop 7\n\ts_nop 7"
                     : "+v"(ac0), "+v"(ac1), "+v"(ac2), "+v"(ac3));

        // ---- gate extraction: col-0 lanes hold D rows (kq*4 + reg) ---------
        if (lr == 0) {
            f4* sg4 = (f4*)sg;
            sg4[16 * w + 0 + kq] = ac0;
            sg4[16 * w + 4 + kq] = ac1;
            sg4[16 * w + 8 + kq] = ac2;
            sg4[16 * w + 12 + kq] = ac3;
        }
        __syncthreads();   // gates ready

        // ---- pointwise (tid<128): c1, h, f16 hi/lo split -------------------
        if (tid < H1_) {
            const float vi = sg[tid];
            const float vf = sg[H1_ + tid];
            const float vg = sg[2 * H1_ + tid];
            const float vo = sg[3 * H1_ + tid];
            c1 = fmaf(sigmoidf_(vf), c1, sigmoidf_(vi) * tanhf_(vg));
            const float h = sigmoidf_(vo) * tanhf_(c1);
            const _Float16 hh = (_Float16)h;
            const _Float16 hl = (_Float16)(h - (float)hh);
            ((_Float16*)sh_hi8)[tid] = hh;
            ((_Float16*)sh_lo8)[tid] = hl;
            h1seq[(size_t)t * H1_ + tid] = h;   // fire-and-forget (f32 exact)
        }
        __syncthreads();   // h f16 arrays ready for next step's B build
    }
}

// ---------------- C1: xp2 = h1seq @ W_ih1^T + (b_ih1 + b_hh1) ---------------
__global__ void xproj2_kernel(const float* __restrict__ h1seq,
                              const float* __restrict__ W_ih1,
                              const float* __restrict__ b_ih1,
                              const float* __restrict__ b_hh1,
                              float* __restrict__ xp2)
{
    const int t = blockIdx.x;
    const int g = threadIdx.x;
    __shared__ f4 sh[H1_ / 4];
    if (g < H1_ / 4) sh[g] = ((const f4*)(h1seq + (size_t)t * H1_))[g];
    __syncthreads();
    const f4* w = (const f4*)(W_ih1 + (size_t)g * H1_);
    float ax = 0.f, ay = 0.f, az = 0.f, aw = 0.f;
#pragma unroll
    for (int k = 0; k < H1_ / 4; ++k) {
        const f4 h4 = sh[k]; const f4 w4 = w[k];
        ax = fmaf(w4.x, h4.x, ax); ay = fmaf(w4.y, h4.y, ay);
        az = fmaf(w4.z, h4.z, az); aw = fmaf(w4.w, h4.w, aw);
    }
    xp2[(size_t)t * G2_ + g] = ((ax + ay) + (az + aw)) + b_ih1[g] + b_hh1[g];
}

// ---------------- B2: layer-2 scan (serial, one block) — R7 version ----------
__global__ __attribute__((amdgpu_flat_work_group_size(256, 256),
                          amdgpu_waves_per_eu(1, 1)))
void lstm2_kernel(const float* __restrict__ xp2,
                  const float* __restrict__ W_hh1,
                  float* __restrict__ h2seq)
{
    const int tid = threadIdx.x;       // gate index 0..255

    __shared__ f4    sh2[H2_ / 4];     // h2 state (64 f32)
    __shared__ float sg2[G2_];         // full gate pre-activations

    const f4* pw = (const f4*)(W_hh1 + (size_t)tid * H2_);
    f4 w_0, w_1, w_2, w_3, w_4, w_5, w_6, w_7,
       w_8, w_9, w_10, w_11, w_12, w_13, w_14, w_15;
    ASM_LOAD_16Q(pw);

    if (tid < H2_ / 4) sh2[tid] = f4{0.f, 0.f, 0.f, 0.f};
    float c2 = 0.0f;                   // owned by tid < 64
    __syncthreads();

    float xp_cur = xp2[tid];

    for (int t = 0; t < T_STEPS; ++t) {
        float xp_next;
        {
            const int tn = (t + 1 < T_STEPS) ? (t + 1) : (T_STEPS - 1);
            xp_next = xp2[(size_t)tn * G2_ + tid];
        }

        float ax = 0.f, ay = 0.f, az = 0.f, aw = 0.f;
#define P1S(k) { const f4 h4 = sh2[k];                                       \
        ax = fmaf(w_##k.x, h4.x, ax); ay = fmaf(w_##k.y, h4.y, ay);          \
        az = fmaf(w_##k.z, h4.z, az); aw = fmaf(w_##k.w, h4.w, aw); }
        REP16(P1S)
#undef P1S
        sg2[tid] = ((ax + ay) + (az + aw)) + xp_cur;
        __syncthreads();   // sg2 ready (also orders prev h2 writes)

        if (tid < H2_) {
            const float vi = sg2[tid];
            const float vf = sg2[H2_ + tid];
            const float vg = sg2[2 * H2_ + tid];
            const float vo = sg2[3 * H2_ + tid];
            c2 = fmaf(sigmoidf_(vf), c2, sigmoidf_(vi) * tanhf_(vg));
            const float h = sigmoidf_(vo) * tanhf_(c2);
            ((float*)sh2)[tid] = h;
            h2seq[(size_t)t * H2_ + tid] = h;
        }
        __syncthreads();   // h2_new ready
        xp_cur = xp_next;
    }
}

// ---------------- D: head out[t,o] = relu(h2[t]) . W_d[o] + b_d --------------
__global__ void head_kernel(const float* __restrict__ h2seq,
                            const float* __restrict__ W_d,
                            const float* __restrict__ b_d,
                            float* __restrict__ out)
{
    const int idx = blockIdx.x * blockDim.x + threadIdx.x;
    if (idx >= T_STEPS * OUT_F) return;
    const int t = idx / OUT_F;
    const int o = idx - t * OUT_F;
    const float* hr = h2seq + (size_t)t * H2_;
    const float* w  = W_d + o * H2_;
    float acc = b_d[o];
#pragma unroll
    for (int j = 0; j < H2_; ++j) acc = fmaf(fmaxf(hr[j], 0.0f), w[j], acc);
    out[idx] = acc;
}

extern "C" void kernel_launch(void* const* d_in, const int* in_sizes, int n_in,
                              void* d_out, int out_size, void* d_ws, size_t ws_size,
                              hipStream_t stream) {
    const float* x     = (const float*)d_in[0];
    const float* W_ih0 = (const float*)d_in[1];
    const float* W_hh0 = (const float*)d_in[2];
    const float* b_ih0 = (const float*)d_in[3];
    const float* b_hh0 = (const float*)d_in[4];
    const float* W_ih1 = (const float*)d_in[5];
    const float* W_hh1 = (const float*)d_in[6];
    const float* b_ih1 = (const float*)d_in[7];
    const float* b_hh1 = (const float*)d_in[8];
    const float* W_d   = (const float*)d_in[9];
    const float* b_d   = (const float*)d_in[10];

    float* out   = (float*)d_out;
    float* xp1   = (float*)d_ws;                       // [1024][512] = 2 MB
    float* h1seq = xp1 + (size_t)T_STEPS * G1_;        // [1024][128] = 512 KB
    float* h2seq = h1seq + (size_t)T_STEPS * H1_;      // [1024][64]  = 256 KB
    float* xp2   = xp1;                                // overlay (xp1 dead after B1)

    hipLaunchKernelGGL(xproj_kernel, dim3(T_STEPS), dim3(G1_), 0, stream,
                       x, W_ih0, b_ih0, b_hh0, xp1);
    hipLaunchKernelGGL(lstm1_kernel, dim3(1), dim3(512), 0, stream,
                       xp1, W_hh0, h1seq);
    hipLaunchKernelGGL(xproj2_kernel, dim3(T_STEPS), dim3(G2_), 0, stream,
                       h1seq, W_ih1, b_ih1, b_hh1, xp2);
    hipLaunchKernelGGL(lstm2_kernel, dim3(1), dim3(256), 0, stream,
                       xp2, W_hh1, h2seq);
    hipLaunchKernelGGL(head_kernel, dim3((T_STEPS * OUT_F + 255) / 256), dim3(256),
                       0, stream, h2seq, W_d, b_d, out);
}